// Round 2
// baseline (132.993 us; speedup 1.0000x reference)
//
#include <hip/hip_runtime.h>
#include <hip/hip_bf16.h>

#define T_SEQ 2048
#define EMB   128
#define H     16
#define BATCH 8
#define BQ    32   // query rows per attention block

// ---------------------------------------------------------------------------
// Kernel 1: QKV projection (fp32 in, fp32 ws out).
// Block = 256 thr covering a 16-row x-tile; thread (row,col) computes
// q/k/v[row][col]. W staged TRANSPOSED in LDS so the inner loop is
// ds_read_b128 on both operands.
// ---------------------------------------------------------------------------
__global__ __launch_bounds__(256) void qkv_kernel(
    const float* __restrict__ x,
    const float* __restrict__ Wq,
    const float* __restrict__ Wk,
    const float* __restrict__ Wv,
    float* __restrict__ Q, float* __restrict__ K, float* __restrict__ V)
{
    __shared__ float Xs[16][132];       // stride 132 ≡ 4 (mod 32): b128-friendly
    __shared__ float Wt[3][16][132];    // transposed: Wt[m][col][d]

    const int tid = threadIdx.x;
    const int r0  = blockIdx.x * 16;    // global row base

    // Stage x tile: 16 rows x 128 fp32. 8 floats (2 x float4) per thread.
    {
        const float* xp = x + (size_t)r0 * EMB;
        const int f   = tid * 8;
        const int row = f >> 7;
        const int d0  = f & 127;
        float4 a = *reinterpret_cast<const float4*>(xp + f);
        float4 b = *reinterpret_cast<const float4*>(xp + f + 4);
        *reinterpret_cast<float4*>(&Xs[row][d0])     = a;
        *reinterpret_cast<float4*>(&Xs[row][d0 + 4]) = b;
    }
    // Stage W transposed: 3 * 2048 fp32, coalesced global reads.
    {
        for (int i = tid; i < 3 * 2048; i += 256) {
            const int m   = i >> 11;
            const int idx = i & 2047;           // = d*16 + col (row-major W)
            const int d   = idx >> 4;
            const int col = idx & 15;
            const float* Wm = (m == 0) ? Wq : (m == 1) ? Wk : Wv;
            Wt[m][col][d] = Wm[idx];
        }
    }
    __syncthreads();

    const int row = tid >> 4;   // 0..15
    const int col = tid & 15;   // 0..15
    float qa = 0.f, ka = 0.f, va = 0.f;
#pragma unroll
    for (int d0 = 0; d0 < 128; d0 += 4) {
        float4 xv = *reinterpret_cast<const float4*>(&Xs[row][d0]);
        float4 wq = *reinterpret_cast<const float4*>(&Wt[0][col][d0]);
        float4 wk = *reinterpret_cast<const float4*>(&Wt[1][col][d0]);
        float4 wv = *reinterpret_cast<const float4*>(&Wt[2][col][d0]);
        qa += xv.x * wq.x + xv.y * wq.y + xv.z * wq.z + xv.w * wq.w;
        ka += xv.x * wk.x + xv.y * wk.y + xv.z * wk.z + xv.w * wk.w;
        va += xv.x * wv.x + xv.y * wv.y + xv.z * wv.z + xv.w * wv.w;
    }
    const size_t o = (size_t)(r0 + row) * H + col;
    Q[o] = qa; K[o] = ka; V[o] = va;
}

// ---------------------------------------------------------------------------
// Kernel 2: causal flash attention (fp32 in/out).
// Grid (64, 8): x -> q-tile (reversed: heavy first), y -> batch.
// Block 256 thr = 32 rows x 8 key-lanes; 64-key tiles staged in LDS
// (stride 20: the 8 key-lanes hit 8 disjoint 4-bank groups -> conflict-free
// float4 reads). Online softmax state replicated across the 8 lanes via
// shfl_xor; final 8-lane acc reduce + float2 store.
// ---------------------------------------------------------------------------
__global__ __launch_bounds__(256) void attn_kernel(
    const float* __restrict__ Q, const float* __restrict__ K,
    const float* __restrict__ V, float* __restrict__ out)
{
    __shared__ float Ks[64][20];
    __shared__ float Vs[64][20];

    const int tid = threadIdx.x;
    const int b   = blockIdx.y;
    const int qt  = 63 - blockIdx.x;        // heavy q-tiles first
    const int i0  = qt * BQ;
    const int row = tid >> 3;               // 0..31
    const int c   = tid & 7;                // 0..7
    const int i   = i0 + row;               // global query row in batch

    const float* Qb = Q + (size_t)b * T_SEQ * H;
    const float* Kb = K + (size_t)b * T_SEQ * H;
    const float* Vb = V + (size_t)b * T_SEQ * H;

    // Load full q row (16 fp32) into registers.
    float q[16];
    {
        const float4* qp = reinterpret_cast<const float4*>(Qb + (size_t)i * H);
        float4 a0 = qp[0], a1 = qp[1], a2 = qp[2], a3 = qp[3];
        q[0]=a0.x; q[1]=a0.y; q[2]=a0.z; q[3]=a0.w;
        q[4]=a1.x; q[5]=a1.y; q[6]=a1.z; q[7]=a1.w;
        q[8]=a2.x; q[9]=a2.y; q[10]=a2.z; q[11]=a2.w;
        q[12]=a3.x; q[13]=a3.y; q[14]=a3.z; q[15]=a3.w;
    }

    float acc[16];
#pragma unroll
    for (int d = 0; d < 16; ++d) acc[d] = 0.f;
    float m = -1e30f, l = 0.f;

    const int nkt = ((i0 + BQ - 1) >> 6) + 1;   // causal tile count (uniform)
    for (int kt = 0; kt < nkt; ++kt) {
        const int j0 = kt * 64;
        // Stage K,V tile: 1024 fp32 each; one float4 per thread, coalesced.
        {
            const int f  = tid * 4;
            const int jl = f >> 4;
            const int d0 = f & 15;
            float4 kv = *reinterpret_cast<const float4*>(Kb + (size_t)j0 * H + f);
            float4 vv = *reinterpret_cast<const float4*>(Vb + (size_t)j0 * H + f);
            *reinterpret_cast<float4*>(&Ks[jl][d0]) = kv;
            *reinterpret_cast<float4*>(&Vs[jl][d0]) = vv;
        }
        __syncthreads();

        // Scores for this lane's 8 keys (vector LDS reads).
        float p[8];
        float tmax = -1e30f;
#pragma unroll
        for (int ii = 0; ii < 8; ++ii) {
            const int jl = ii * 8 + c;
            const float4* kp = reinterpret_cast<const float4*>(&Ks[jl][0]);
            float4 k0 = kp[0], k1 = kp[1], k2 = kp[2], k3 = kp[3];
            float s = q[0]*k0.x + q[1]*k0.y + q[2]*k0.z + q[3]*k0.w
                    + q[4]*k1.x + q[5]*k1.y + q[6]*k1.z + q[7]*k1.w
                    + q[8]*k2.x + q[9]*k2.y + q[10]*k2.z + q[11]*k2.w
                    + q[12]*k3.x + q[13]*k3.y + q[14]*k3.z + q[15]*k3.w;
            s *= 0.25f;                         // 1/sqrt(16)
            if (j0 + jl > i) s = -1e30f;        // causal mask (finite: no NaN)
            p[ii] = s;
            tmax = fmaxf(tmax, s);
        }
        // Row max across the 8 lanes.
        tmax = fmaxf(tmax, __shfl_xor(tmax, 1));
        tmax = fmaxf(tmax, __shfl_xor(tmax, 2));
        tmax = fmaxf(tmax, __shfl_xor(tmax, 4));
        const float m_new = fmaxf(m, tmax);
        const float alpha = __expf(m - m_new);  // first tile: exp(-1e30) -> 0

        float psum = 0.f;
#pragma unroll
        for (int ii = 0; ii < 8; ++ii) {
            const float e = __expf(p[ii] - m_new);
            p[ii] = e;
            psum += e;
        }
        psum += __shfl_xor(psum, 1);
        psum += __shfl_xor(psum, 2);
        psum += __shfl_xor(psum, 4);
        l = l * alpha + psum;
        m = m_new;

#pragma unroll
        for (int d = 0; d < 16; ++d) acc[d] *= alpha;
#pragma unroll
        for (int ii = 0; ii < 8; ++ii) {
            const int jl = ii * 8 + c;
            const float e = p[ii];
            const float4* vp = reinterpret_cast<const float4*>(&Vs[jl][0]);
            float4 v0 = vp[0], v1 = vp[1], v2 = vp[2], v3 = vp[3];
            acc[0]  += e * v0.x; acc[1]  += e * v0.y;
            acc[2]  += e * v0.z; acc[3]  += e * v0.w;
            acc[4]  += e * v1.x; acc[5]  += e * v1.y;
            acc[6]  += e * v1.z; acc[7]  += e * v1.w;
            acc[8]  += e * v2.x; acc[9]  += e * v2.y;
            acc[10] += e * v2.z; acc[11] += e * v2.w;
            acc[12] += e * v3.x; acc[13] += e * v3.y;
            acc[14] += e * v3.z; acc[15] += e * v3.w;
        }
        __syncthreads();   // before next tile overwrites LDS
    }

    // Reduce acc across the 8 lanes of this row; all lanes end with full sums.
#pragma unroll
    for (int d = 0; d < 16; ++d) {
        float a = acc[d];
        a += __shfl_xor(a, 1);
        a += __shfl_xor(a, 2);
        a += __shfl_xor(a, 4);
        acc[d] = a;
    }
    const float inv = 1.0f / l;
    float* op = out + ((size_t)(b * T_SEQ) + i) * H;
    float2 r;
    r.x = acc[2 * c]     * inv;
    r.y = acc[2 * c + 1] * inv;
    *reinterpret_cast<float2*>(op + 2 * c) = r;
}

// ---------------------------------------------------------------------------
extern "C" void kernel_launch(void* const* d_in, const int* in_sizes, int n_in,
                              void* d_out, int out_size, void* d_ws, size_t ws_size,
                              hipStream_t stream)
{
    const float* x  = (const float*)d_in[0];
    const float* Wq = (const float*)d_in[1];
    const float* Wk = (const float*)d_in[2];
    const float* Wv = (const float*)d_in[3];
    float* out = (float*)d_out;

    float* Qw = (float*)d_ws;                       // 1 MB
    float* Kw = Qw + (size_t)BATCH * T_SEQ * H;     // 1 MB
    float* Vw = Kw + (size_t)BATCH * T_SEQ * H;     // 1 MB

    qkv_kernel<<<BATCH * T_SEQ / 16, 256, 0, stream>>>(x, Wq, Wk, Wv, Qw, Kw, Vw);
    attn_kernel<<<dim3(T_SEQ / BQ, BATCH), 256, 0, stream>>>(Qw, Kw, Vw, out);
}

// Round 4
// 112.835 us; speedup vs baseline: 1.1787x; 1.1787x over previous
//
#include <hip/hip_runtime.h>
#include <hip/hip_bf16.h>

#define T_SEQ 2048
#define EMB   128
#define H     16
#define BATCH 8
#define BQ    32          // query rows per attention block
#define CHUNK 512         // keys per phase-1 block
#define MAXP  4           // max partials per row (2048/512)

// ---------------------------------------------------------------------------
// Kernel 1: QKV projection (fp32). Block = 256 thr = 16 col-threads x 16
// row-groups x 4 rows each -> 64 rows/block, 256 blocks.
// Per 4 dims: 4 Xs b128 + 3 Wt b128 LDS reads serve 48 FMA.
// ---------------------------------------------------------------------------
__global__ __launch_bounds__(256) void qkv_kernel(
    const float* __restrict__ x,
    const float* __restrict__ Wq,
    const float* __restrict__ Wk,
    const float* __restrict__ Wv,
    float* __restrict__ Q, float* __restrict__ K, float* __restrict__ V)
{
    __shared__ float Xs[64][132];       // 33.8 KB; stride 132 = 4 mod 32
    __shared__ float Wt[3][16][132];    // 25.3 KB; transposed W

    const int tid = threadIdx.x;
    const int r0  = blockIdx.x * 64;

    // Stage x tile: 64 rows x 128 = 8192 floats; 8 float4 per thread.
    {
        const float* xp = x + (size_t)r0 * EMB;
#pragma unroll
        for (int p = 0; p < 8; ++p) {
            const int idx = p * 1024 + tid * 4;
            const int row = idx >> 7;
            const int d   = idx & 127;
            *reinterpret_cast<float4*>(&Xs[row][d]) =
                *reinterpret_cast<const float4*>(xp + idx);
        }
    }
    // Stage W transposed: 3*2048 floats; 6 float4 loads + scatter writes.
    // NOTE: index into Wm with rem (offset WITHIN the matrix), not flat!
    {
#pragma unroll
        for (int p = 0; p < 6; ++p) {
            const int idx4 = tid + p * 256;
            const int flat = idx4 * 4;
            const int m    = flat >> 11;
            const int rem  = flat & 2047;       // = d*16 + col within matrix m
            const int d    = rem >> 4;
            const int c0   = rem & 15;
            const float* Wm = (m == 0) ? Wq : (m == 1) ? Wk : Wv;
            float4 w = *reinterpret_cast<const float4*>(Wm + rem);
            Wt[m][c0    ][d] = w.x;
            Wt[m][c0 + 1][d] = w.y;
            Wt[m][c0 + 2][d] = w.z;
            Wt[m][c0 + 3][d] = w.w;
        }
    }
    __syncthreads();

    const int col = tid & 15;
    const int rg  = tid >> 4;           // 0..15, rows rg*4..rg*4+3
    float qa[4] = {0,0,0,0}, ka[4] = {0,0,0,0}, va[4] = {0,0,0,0};
#pragma unroll
    for (int d0 = 0; d0 < 128; d0 += 4) {
        float4 wq = *reinterpret_cast<const float4*>(&Wt[0][col][d0]);
        float4 wk = *reinterpret_cast<const float4*>(&Wt[1][col][d0]);
        float4 wv = *reinterpret_cast<const float4*>(&Wt[2][col][d0]);
#pragma unroll
        for (int rr = 0; rr < 4; ++rr) {
            float4 xv = *reinterpret_cast<const float4*>(&Xs[rg * 4 + rr][d0]);
            qa[rr] += xv.x * wq.x + xv.y * wq.y + xv.z * wq.z + xv.w * wq.w;
            ka[rr] += xv.x * wk.x + xv.y * wk.y + xv.z * wk.z + xv.w * wk.w;
            va[rr] += xv.x * wv.x + xv.y * wv.y + xv.z * wv.z + xv.w * wv.w;
        }
    }
#pragma unroll
    for (int rr = 0; rr < 4; ++rr) {
        const size_t o = (size_t)(r0 + rg * 4 + rr) * H + col;
        Q[o] = qa[rr]; K[o] = ka[rr]; V[o] = va[rr];
    }
}

// ---------------------------------------------------------------------------
// Kernel 2a: phase-1 flash attention over a 512-key chunk.
// Grid: 1280 blocks = 8 batches x 160 (qt,chunk) pairs, all co-resident.
// Block 256 thr = 32 rows x 8 key-lanes; writes UNNORMALIZED partials
// (acc[16], m, l) stride-18 to ws.
// ---------------------------------------------------------------------------
__global__ __launch_bounds__(256) void attn_phase1(
    const float* __restrict__ Q, const float* __restrict__ K,
    const float* __restrict__ V, float* __restrict__ P2)
{
    __shared__ float Ks[64][20];
    __shared__ float Vs[64][20];

    const int tid = threadIdx.x;
    const int w   = blockIdx.x;
    const int b   = w / 160;
    const int r   = 159 - (w % 160);    // heavy (many-tile) blocks first
    int qt, cch;
    if (r < 16)      { qt = r;                 cch = 0; }
    else if (r < 48) { qt = 16 + (r - 16) / 2; cch = (r - 16) % 2; }
    else if (r < 96) { qt = 32 + (r - 48) / 3; cch = (r - 48) % 3; }
    else             { qt = 48 + (r - 96) / 4; cch = (r - 96) % 4; }

    const int i0   = qt * BQ;
    const int kbeg = cch * CHUNK;
    const int kend = min(i0 + BQ, kbeg + CHUNK);
    const int ntiles = (kend - kbeg + 63) >> 6;

    const int row = tid >> 3;           // 0..31
    const int c   = tid & 7;            // 0..7
    const int i   = i0 + row;

    const float* Qb = Q + (size_t)b * T_SEQ * H;
    const float* Kb = K + (size_t)b * T_SEQ * H;
    const float* Vb = V + (size_t)b * T_SEQ * H;

    float q[16];
    {
        const float4* qp = reinterpret_cast<const float4*>(Qb + (size_t)i * H);
        float4 a0 = qp[0], a1 = qp[1], a2 = qp[2], a3 = qp[3];
        q[0]=a0.x; q[1]=a0.y; q[2]=a0.z; q[3]=a0.w;
        q[4]=a1.x; q[5]=a1.y; q[6]=a1.z; q[7]=a1.w;
        q[8]=a2.x; q[9]=a2.y; q[10]=a2.z; q[11]=a2.w;
        q[12]=a3.x; q[13]=a3.y; q[14]=a3.z; q[15]=a3.w;
    }

    float acc[16];
#pragma unroll
    for (int d = 0; d < 16; ++d) acc[d] = 0.f;
    float m = -1e30f, l = 0.f;

    for (int kt = 0; kt < ntiles; ++kt) {
        const int j0 = kbeg + kt * 64;
        // Stage K,V tile (guarded against reading past row 2048).
        {
            const int f    = tid * 4;
            const int jl   = f >> 4;
            const int d0   = f & 15;
            const int jrow = j0 + jl;
            float4 kv = make_float4(0.f, 0.f, 0.f, 0.f), vv = kv;
            if (jrow < T_SEQ) {
                kv = *reinterpret_cast<const float4*>(Kb + (size_t)jrow * H + d0);
                vv = *reinterpret_cast<const float4*>(Vb + (size_t)jrow * H + d0);
            }
            *reinterpret_cast<float4*>(&Ks[jl][d0]) = kv;
            *reinterpret_cast<float4*>(&Vs[jl][d0]) = vv;
        }
        __syncthreads();

        float p[8];
        float tmax = -1e30f;
#pragma unroll
        for (int ii = 0; ii < 8; ++ii) {
            const int jl = ii * 8 + c;
            const float4* kp = reinterpret_cast<const float4*>(&Ks[jl][0]);
            float4 k0 = kp[0], k1 = kp[1], k2 = kp[2], k3 = kp[3];
            float s = q[0]*k0.x + q[1]*k0.y + q[2]*k0.z + q[3]*k0.w
                    + q[4]*k1.x + q[5]*k1.y + q[6]*k1.z + q[7]*k1.w
                    + q[8]*k2.x + q[9]*k2.y + q[10]*k2.z + q[11]*k2.w
                    + q[12]*k3.x + q[13]*k3.y + q[14]*k3.z + q[15]*k3.w;
            s *= 0.25f;
            if (j0 + jl > i) s = -1e30f;    // causal mask (finite)
            p[ii] = s;
            tmax = fmaxf(tmax, s);
        }
        tmax = fmaxf(tmax, __shfl_xor(tmax, 1));
        tmax = fmaxf(tmax, __shfl_xor(tmax, 2));
        tmax = fmaxf(tmax, __shfl_xor(tmax, 4));
        const float m_new = fmaxf(m, tmax);
        const float alpha = __expf(m - m_new);

        float psum = 0.f;
#pragma unroll
        for (int ii = 0; ii < 8; ++ii) {
            const float e = __expf(p[ii] - m_new);
            p[ii] = e;
            psum += e;
        }
        psum += __shfl_xor(psum, 1);
        psum += __shfl_xor(psum, 2);
        psum += __shfl_xor(psum, 4);
        l = l * alpha + psum;
        m = m_new;

#pragma unroll
        for (int d = 0; d < 16; ++d) acc[d] *= alpha;
#pragma unroll
        for (int ii = 0; ii < 8; ++ii) {
            const int jl = ii * 8 + c;
            const float e = p[ii];
            const float4* vp = reinterpret_cast<const float4*>(&Vs[jl][0]);
            float4 v0 = vp[0], v1 = vp[1], v2 = vp[2], v3 = vp[3];
            acc[0]  += e * v0.x; acc[1]  += e * v0.y;
            acc[2]  += e * v0.z; acc[3]  += e * v0.w;
            acc[4]  += e * v1.x; acc[5]  += e * v1.y;
            acc[6]  += e * v1.z; acc[7]  += e * v1.w;
            acc[8]  += e * v2.x; acc[9]  += e * v2.y;
            acc[10] += e * v2.z; acc[11] += e * v2.w;
            acc[12] += e * v3.x; acc[13] += e * v3.y;
            acc[14] += e * v3.z; acc[15] += e * v3.w;
        }
        __syncthreads();
    }

    // 8-lane reduce; all lanes end with full row sums.
#pragma unroll
    for (int d = 0; d < 16; ++d) {
        float a = acc[d];
        a += __shfl_xor(a, 1);
        a += __shfl_xor(a, 2);
        a += __shfl_xor(a, 4);
        acc[d] = a;
    }
    // Write unnormalized partial: [acc0..15, m, l] at slot (row, chunk).
    float* pp = P2 + ((size_t)(b * T_SEQ + i) * MAXP + cch) * 18;
    float2 rr;
    rr.x = acc[2 * c];
    rr.y = acc[2 * c + 1];
    *reinterpret_cast<float2*>(pp + 2 * c) = rr;
    if (c == 0) { pp[16] = m; pp[17] = l; }
}

// ---------------------------------------------------------------------------
// Kernel 2b: combine partials. One thread per (row, dim).
// ---------------------------------------------------------------------------
__global__ __launch_bounds__(256) void attn_phase2(
    const float* __restrict__ P2, float* __restrict__ out)
{
    const int gid = blockIdx.x * 256 + threadIdx.x;   // 0..262143
    const int row = gid >> 4;
    const int d   = gid & 15;
    const int ib  = row & (T_SEQ - 1);
    const int nc  = (ib >> 9) + 1;                    // chunks this row used
    const float* base = P2 + (size_t)row * (MAXP * 18);

    float M = -1e30f;
    for (int p = 0; p < nc; ++p) M = fmaxf(M, base[p * 18 + 16]);
    float L = 0.f, o = 0.f;
    for (int p = 0; p < nc; ++p) {
        const float wgt = __expf(base[p * 18 + 16] - M);
        L += wgt * base[p * 18 + 17];
        o += wgt * base[p * 18 + d];
    }
    out[gid] = o / L;
}

// ---------------------------------------------------------------------------
// Fallback: round-2 single-pass attention (used only if ws too small).
// ---------------------------------------------------------------------------
__global__ __launch_bounds__(256) void attn_single(
    const float* __restrict__ Q, const float* __restrict__ K,
    const float* __restrict__ V, float* __restrict__ out)
{
    __shared__ float Ks[64][20];
    __shared__ float Vs[64][20];

    const int tid = threadIdx.x;
    const int b   = blockIdx.y;
    const int qt  = 63 - blockIdx.x;
    const int i0  = qt * BQ;
    const int row = tid >> 3;
    const int c   = tid & 7;
    const int i   = i0 + row;

    const float* Qb = Q + (size_t)b * T_SEQ * H;
    const float* Kb = K + (size_t)b * T_SEQ * H;
    const float* Vb = V + (size_t)b * T_SEQ * H;

    float q[16];
    {
        const float4* qp = reinterpret_cast<const float4*>(Qb + (size_t)i * H);
        float4 a0 = qp[0], a1 = qp[1], a2 = qp[2], a3 = qp[3];
        q[0]=a0.x; q[1]=a0.y; q[2]=a0.z; q[3]=a0.w;
        q[4]=a1.x; q[5]=a1.y; q[6]=a1.z; q[7]=a1.w;
        q[8]=a2.x; q[9]=a2.y; q[10]=a2.z; q[11]=a2.w;
        q[12]=a3.x; q[13]=a3.y; q[14]=a3.z; q[15]=a3.w;
    }
    float acc[16];
#pragma unroll
    for (int d = 0; d < 16; ++d) acc[d] = 0.f;
    float m = -1e30f, l = 0.f;

    const int nkt = ((i0 + BQ - 1) >> 6) + 1;
    for (int kt = 0; kt < nkt; ++kt) {
        const int j0 = kt * 64;
        {
            const int f  = tid * 4;
            const int jl = f >> 4;
            const int d0 = f & 15;
            float4 kv = *reinterpret_cast<const float4*>(Kb + (size_t)j0 * H + f);
            float4 vv = *reinterpret_cast<const float4*>(Vb + (size_t)j0 * H + f);
            *reinterpret_cast<float4*>(&Ks[jl][d0]) = kv;
            *reinterpret_cast<float4*>(&Vs[jl][d0]) = vv;
        }
        __syncthreads();
        float p[8];
        float tmax = -1e30f;
#pragma unroll
        for (int ii = 0; ii < 8; ++ii) {
            const int jl = ii * 8 + c;
            const float4* kp = reinterpret_cast<const float4*>(&Ks[jl][0]);
            float4 k0 = kp[0], k1 = kp[1], k2 = kp[2], k3 = kp[3];
            float s = q[0]*k0.x + q[1]*k0.y + q[2]*k0.z + q[3]*k0.w
                    + q[4]*k1.x + q[5]*k1.y + q[6]*k1.z + q[7]*k1.w
                    + q[8]*k2.x + q[9]*k2.y + q[10]*k2.z + q[11]*k2.w
                    + q[12]*k3.x + q[13]*k3.y + q[14]*k3.z + q[15]*k3.w;
            s *= 0.25f;
            if (j0 + jl > i) s = -1e30f;
            p[ii] = s;
            tmax = fmaxf(tmax, s);
        }
        tmax = fmaxf(tmax, __shfl_xor(tmax, 1));
        tmax = fmaxf(tmax, __shfl_xor(tmax, 2));
        tmax = fmaxf(tmax, __shfl_xor(tmax, 4));
        const float m_new = fmaxf(m, tmax);
        const float alpha = __expf(m - m_new);
        float psum = 0.f;
#pragma unroll
        for (int ii = 0; ii < 8; ++ii) {
            const float e = __expf(p[ii] - m_new);
            p[ii] = e; psum += e;
        }
        psum += __shfl_xor(psum, 1);
        psum += __shfl_xor(psum, 2);
        psum += __shfl_xor(psum, 4);
        l = l * alpha + psum;
        m = m_new;
#pragma unroll
        for (int d = 0; d < 16; ++d) acc[d] *= alpha;
#pragma unroll
        for (int ii = 0; ii < 8; ++ii) {
            const int jl = ii * 8 + c;
            const float e = p[ii];
            const float4* vp = reinterpret_cast<const float4*>(&Vs[jl][0]);
            float4 v0 = vp[0], v1 = vp[1], v2 = vp[2], v3 = vp[3];
            acc[0]  += e * v0.x; acc[1]  += e * v0.y;
            acc[2]  += e * v0.z; acc[3]  += e * v0.w;
            acc[4]  += e * v1.x; acc[5]  += e * v1.y;
            acc[6]  += e * v1.z; acc[7]  += e * v1.w;
            acc[8]  += e * v2.x; acc[9]  += e * v2.y;
            acc[10] += e * v2.z; acc[11] += e * v2.w;
            acc[12] += e * v3.x; acc[13] += e * v3.y;
            acc[14] += e * v3.z; acc[15] += e * v3.w;
        }
        __syncthreads();
    }
#pragma unroll
    for (int d = 0; d < 16; ++d) {
        float a = acc[d];
        a += __shfl_xor(a, 1);
        a += __shfl_xor(a, 2);
        a += __shfl_xor(a, 4);
        acc[d] = a;
    }
    const float inv = 1.0f / l;
    float* op = out + ((size_t)(b * T_SEQ) + i) * H;
    float2 rr;
    rr.x = acc[2 * c] * inv;
    rr.y = acc[2 * c + 1] * inv;
    *reinterpret_cast<float2*>(op + 2 * c) = rr;
}

// ---------------------------------------------------------------------------
extern "C" void kernel_launch(void* const* d_in, const int* in_sizes, int n_in,
                              void* d_out, int out_size, void* d_ws, size_t ws_size,
                              hipStream_t stream)
{
    const float* x  = (const float*)d_in[0];
    const float* Wq = (const float*)d_in[1];
    const float* Wk = (const float*)d_in[2];
    const float* Wv = (const float*)d_in[3];
    float* out = (float*)d_out;

    const size_t NQ = (size_t)BATCH * T_SEQ * H;    // 262144
    float* Qw = (float*)d_ws;
    float* Kw = Qw + NQ;
    float* Vw = Kw + NQ;
    float* P2 = Vw + NQ;                            // 16384*4*18 floats

    const size_t need = (3 * NQ + (size_t)BATCH * T_SEQ * MAXP * 18) * sizeof(float);

    qkv_kernel<<<BATCH * T_SEQ / 64, 256, 0, stream>>>(x, Wq, Wk, Wv, Qw, Kw, Vw);
    if (ws_size >= need) {
        attn_phase1<<<BATCH * 160, 256, 0, stream>>>(Qw, Kw, Vw, P2);
        attn_phase2<<<BATCH * T_SEQ * H / 256, 256, 0, stream>>>(P2, out);
    } else {
        attn_single<<<dim3(T_SEQ / BQ, BATCH), 256, 0, stream>>>(Qw, Kw, Vw, out);
    }
}